// Round 1
// baseline (657.740 us; speedup 1.0000x reference)
//
#include <hip/hip_runtime.h>

typedef __bf16 bf16x8 __attribute__((ext_vector_type(8)));
typedef __bf16 bf16x4 __attribute__((ext_vector_type(4)));
typedef float floatx4 __attribute__((ext_vector_type(4)));

#define EMB 1024
#define MROWS 4096
#define HIDN 4096

// ---------------------------------------------------------------- helpers
__device__ __forceinline__ void load_lds16(const __bf16* g, __bf16* l) {
    __builtin_amdgcn_global_load_lds(
        (const __attribute__((address_space(1))) void*)g,
        (__attribute__((address_space(3))) void*)l, 16, 0, 0);
}

// ------------------------------------------------- fp32 -> bf16 transpose
// in: [R][C] fp32, out: [C][R] bf16
__global__ void transpose_cast_kernel(const float* __restrict__ in,
                                      __bf16* __restrict__ out, int R, int C) {
    __shared__ float tile[32][33];
    int tx = threadIdx.x, ty = threadIdx.y;
    int c0 = blockIdx.x * 32, r0 = blockIdx.y * 32;
#pragma unroll
    for (int i = 0; i < 32; i += 8)
        tile[ty + i][tx] = in[(size_t)(r0 + ty + i) * C + c0 + tx];
    __syncthreads();
#pragma unroll
    for (int i = 0; i < 32; i += 8)
        out[(size_t)(c0 + ty + i) * R + r0 + tx] = (__bf16)tile[tx][ty + i];
}

// ------------------------------------------------------ fp32 -> bf16 cast
__global__ void cast_bf16_kernel(const float* __restrict__ in,
                                 __bf16* __restrict__ out, int n) {
    int i = (blockIdx.x * 256 + threadIdx.x) * 4;
    if (i >= n) return;
    float4 v = *(const float4*)(in + i);
    bf16x4 o;
    o[0] = (__bf16)v.x; o[1] = (__bf16)v.y; o[2] = (__bf16)v.z; o[3] = (__bf16)v.w;
    *(bf16x4*)(out + i) = o;
}

// ------------------------------------------------------------- GEMM (NT)
// C[M][N] = A[M][K] * Bt[N][K]^T, bf16 in, fp32 accum.
// epilogue: v = acc * (col<split ? scale0 : scale1) + bias[col]; opt relu;
// store bf16 or fp32.
template <int STORE_BF16, int RELU>
__launch_bounds__(256, 2)
__global__ void gemm_bt(const __bf16* __restrict__ A, const __bf16* __restrict__ Bt,
                        void* __restrict__ Cv, const float* __restrict__ bias,
                        int M, int N, int Kd, float scale0, float scale1, int split) {
    __shared__ alignas(16) __bf16 As[128 * 32];
    __shared__ alignas(16) __bf16 Bs[128 * 32];
    int tid  = threadIdx.x;
    int wv   = tid >> 6, lane = tid & 63;
    int bn   = blockIdx.x * 128, bm = blockIdx.y * 128;
    int wm   = (wv & 1) * 64, wn = (wv >> 1) * 64;
    int l16  = lane & 15, g16 = lane >> 4;

    const __bf16* ag0 = A  + (size_t)(bm + (tid >> 2)) * Kd + (tid & 3) * 8;
    const __bf16* ag1 = ag0 + (size_t)64 * Kd;
    const __bf16* bg0 = Bt + (size_t)(bn + (tid >> 2)) * Kd + (tid & 3) * 8;
    const __bf16* bg1 = bg0 + (size_t)64 * Kd;
    __bf16* al0 = &As[tid * 8];
    __bf16* al1 = &As[2048 + tid * 8];
    __bf16* bl0 = &Bs[tid * 8];
    __bf16* bl1 = &Bs[2048 + tid * 8];

    floatx4 acc[4][4] = {};

    for (int k0 = 0; k0 < Kd; k0 += 32) {
        __syncthreads();
        load_lds16(ag0, al0); load_lds16(ag1, al1);
        load_lds16(bg0, bl0); load_lds16(bg1, bl1);
        ag0 += 32; ag1 += 32; bg0 += 32; bg1 += 32;
        __syncthreads();
        bf16x8 af[4], bfr[4];
#pragma unroll
        for (int i = 0; i < 4; ++i)
            af[i] = *(const bf16x8*)&As[(wm + i * 16 + l16) * 32 + g16 * 8];
#pragma unroll
        for (int j = 0; j < 4; ++j)
            bfr[j] = *(const bf16x8*)&Bs[(wn + j * 16 + l16) * 32 + g16 * 8];
#pragma unroll
        for (int i = 0; i < 4; ++i)
#pragma unroll
            for (int j = 0; j < 4; ++j)
                acc[i][j] = __builtin_amdgcn_mfma_f32_16x16x32_bf16(af[i], bfr[j], acc[i][j], 0, 0, 0);
    }

#pragma unroll
    for (int j = 0; j < 4; ++j) {
        int col  = bn + wn + j * 16 + l16;
        float sc = (col < split) ? scale0 : scale1;
        float bv = bias ? bias[col] : 0.f;
#pragma unroll
        for (int i = 0; i < 4; ++i) {
            int row0 = bm + wm + i * 16 + g16 * 4;
#pragma unroll
            for (int r = 0; r < 4; ++r) {
                float v = acc[i][j][r] * sc + bv;
                if (RELU) v = fmaxf(v, 0.f);
                size_t idx = (size_t)(row0 + r) * N + col;
                if (STORE_BF16) ((__bf16*)Cv)[idx] = (__bf16)v;
                else            ((float*)Cv)[idx]  = v;
            }
        }
    }
}

// ------------------------------------------------------- flash attention
// q: [b,t,*] with head h at col h*64, row stride ldq. k/v same with ldk.
// out: [b,t,h,s] bf16 row stride 1024. scale already folded into q,k.
__launch_bounds__(256, 2)
__global__ void attn_kernel(const __bf16* __restrict__ qb, const __bf16* __restrict__ kb,
                            const __bf16* __restrict__ vb, int ldq, int ldk,
                            __bf16* __restrict__ out, int causal, int Tc) {
    constexpr int T = 1024;
    __shared__ alignas(16) __bf16 Qs[64 * 72];
    __shared__ alignas(16) __bf16 Ks[64 * 72];
    __shared__ alignas(16) __bf16 Vt[64 * 72];
    __shared__ alignas(16) __bf16 Ps[4][16 * 72];

    int tid = threadIdx.x;
    int wv = tid >> 6, lane = tid & 63;
    int qt = blockIdx.x, h = blockIdx.y, b = blockIdx.z;
    int l16 = lane & 15, g16 = lane >> 4;

    // stage Q tile (64 rows x 64 cols), padded stride 72
#pragma unroll
    for (int cc = 0; cc < 2; ++cc) {
        int c = tid + cc * 256;
        int r = c >> 3, s8 = (c & 7) * 8;
        bf16x8 qv = *(const bf16x8*)(qb + (size_t)(b * T + qt * 64 + r) * ldq + h * 64 + s8);
        *(bf16x8*)&Qs[r * 72 + s8] = qv;
    }

    floatx4 oacc[4] = {};
    float mi[4], li[4];
#pragma unroll
    for (int r = 0; r < 4; ++r) { mi[r] = -1e30f; li[r] = 0.f; }

    int ktmax = causal ? (qt + 1) : (Tc / 64);
    for (int kt = 0; kt < ktmax; ++kt) {
        __syncthreads();
        // stage K and V^T
#pragma unroll
        for (int cc = 0; cc < 2; ++cc) {
            int c = tid + cc * 256;
            int kr = c >> 3, s8 = (c & 7) * 8;
            size_t goff = (size_t)(b * Tc + kt * 64 + kr) * ldk + h * 64 + s8;
            bf16x8 kv8 = *(const bf16x8*)(kb + goff);
            *(bf16x8*)&Ks[kr * 72 + s8] = kv8;
            bf16x8 vv8 = *(const bf16x8*)(vb + goff);
#pragma unroll
            for (int jj = 0; jj < 8; ++jj) Vt[(s8 + jj) * 72 + kr] = vv8[jj];
        }
        __syncthreads();

        // scores: S[16q x 64k] per wave
        floatx4 sacc[4] = {};
#pragma unroll
        for (int kk = 0; kk < 2; ++kk) {
            bf16x8 aq = *(const bf16x8*)&Qs[(wv * 16 + l16) * 72 + kk * 32 + g16 * 8];
#pragma unroll
            for (int j = 0; j < 4; ++j) {
                bf16x8 bk = *(const bf16x8*)&Ks[(j * 16 + l16) * 72 + kk * 32 + g16 * 8];
                sacc[j] = __builtin_amdgcn_mfma_f32_16x16x32_bf16(aq, bk, sacc[j], 0, 0, 0);
            }
        }
        if (causal && kt == qt) {
#pragma unroll
            for (int j = 0; j < 4; ++j)
#pragma unroll
                for (int r = 0; r < 4; ++r)
                    if (j * 16 + l16 > wv * 16 + g16 * 4 + r) sacc[j][r] = -1e30f;
        }

        // online softmax (row = g16*4 + r, 16 lanes/group hold the 16 cols/tile)
#pragma unroll
        for (int r = 0; r < 4; ++r) {
            float mt = fmaxf(fmaxf(sacc[0][r], sacc[1][r]), fmaxf(sacc[2][r], sacc[3][r]));
            mt = fmaxf(mt, __shfl_xor(mt, 1));
            mt = fmaxf(mt, __shfl_xor(mt, 2));
            mt = fmaxf(mt, __shfl_xor(mt, 4));
            mt = fmaxf(mt, __shfl_xor(mt, 8));
            float mnew  = fmaxf(mi[r], mt);
            float alpha = __expf(mi[r] - mnew);
            mi[r] = mnew;
            float ls = 0.f;
#pragma unroll
            for (int j = 0; j < 4; ++j) {
                float p = __expf(sacc[j][r] - mnew);
                sacc[j][r] = p;
                ls += p;
            }
            ls += __shfl_xor(ls, 1); ls += __shfl_xor(ls, 2);
            ls += __shfl_xor(ls, 4); ls += __shfl_xor(ls, 8);
            li[r] = li[r] * alpha + ls;
            oacc[0][r] *= alpha; oacc[1][r] *= alpha;
            oacc[2][r] *= alpha; oacc[3][r] *= alpha;
#pragma unroll
            for (int j = 0; j < 4; ++j)
                Ps[wv][(g16 * 4 + r) * 72 + j * 16 + l16] = (__bf16)sacc[j][r];
        }
        __syncthreads();

        // O += P @ V
#pragma unroll
        for (int kk = 0; kk < 2; ++kk) {
            bf16x8 ap = *(const bf16x8*)&Ps[wv][l16 * 72 + kk * 32 + g16 * 8];
#pragma unroll
            for (int j = 0; j < 4; ++j) {
                bf16x8 bv2 = *(const bf16x8*)&Vt[(j * 16 + l16) * 72 + kk * 32 + g16 * 8];
                oacc[j] = __builtin_amdgcn_mfma_f32_16x16x32_bf16(ap, bv2, oacc[j], 0, 0, 0);
            }
        }
    }

#pragma unroll
    for (int r = 0; r < 4; ++r) {
        float inv = 1.f / li[r];
        int qrow = qt * 64 + wv * 16 + g16 * 4 + r;
#pragma unroll
        for (int j = 0; j < 4; ++j)
            out[(size_t)(b * T + qrow) * EMB + h * 64 + j * 16 + l16] = (__bf16)(oacc[j][r] * inv);
    }
}

// ------------------------------------------------- residual + layernorm
// y = LN(A_row + B_row) * g + b ; write fp32 (outf) and optional bf16 (outb)
__launch_bounds__(256)
__global__ void ln_kernel(const float* __restrict__ A, const float* __restrict__ Bv,
                          const float* __restrict__ g, const float* __restrict__ be,
                          float* __restrict__ outf, __bf16* __restrict__ outb) {
    __shared__ float red[8];
    int row = blockIdx.x, tid = threadIdx.x;
    const float4* a4 = (const float4*)(A + (size_t)row * EMB);
    const float4* b4 = (const float4*)(Bv + (size_t)row * EMB);
    float4 v = a4[tid], u = b4[tid];
    v.x += u.x; v.y += u.y; v.z += u.z; v.w += u.w;
    float s  = v.x + v.y + v.z + v.w;
    float ss = v.x * v.x + v.y * v.y + v.z * v.z + v.w * v.w;
#pragma unroll
    for (int o = 1; o < 64; o <<= 1) { s += __shfl_xor(s, o); ss += __shfl_xor(ss, o); }
    if ((tid & 63) == 0) { red[(tid >> 6) * 2] = s; red[(tid >> 6) * 2 + 1] = ss; }
    __syncthreads();
    s  = red[0] + red[2] + red[4] + red[6];
    ss = red[1] + red[3] + red[5] + red[7];
    float mu  = s * (1.0f / 1024.0f);
    float var = ss * (1.0f / 1024.0f) - mu * mu;
    float rs  = rsqrtf(var + 1e-5f);
    float4 gg = ((const float4*)g)[tid];
    float4 bb = ((const float4*)be)[tid];
    float4 y;
    y.x = (v.x - mu) * rs * gg.x + bb.x;
    y.y = (v.y - mu) * rs * gg.y + bb.y;
    y.z = (v.z - mu) * rs * gg.z + bb.z;
    y.w = (v.w - mu) * rs * gg.w + bb.w;
    ((float4*)(outf + (size_t)row * EMB))[tid] = y;
    if (outb) {
        bf16x4 o;
        o[0] = (__bf16)y.x; o[1] = (__bf16)y.y; o[2] = (__bf16)y.z; o[3] = (__bf16)y.w;
        *(bf16x4*)(outb + (size_t)row * EMB + tid * 4) = o;
    }
}

// ---------------------------------------------------------------- launch
extern "C" void kernel_launch(void* const* d_in, const int* in_sizes, int n_in,
                              void* d_out, int out_size, void* d_ws, size_t ws_size,
                              hipStream_t stream) {
    const float* x     = (const float*)d_in[0];
    const float* ctx   = (const float*)d_in[1];
    const float* sa_wq = (const float*)d_in[2];
    const float* sa_wk = (const float*)d_in[3];
    const float* sa_wv = (const float*)d_in[4];
    const float* sa_wo = (const float*)d_in[5];
    const float* sa_bo = (const float*)d_in[6];
    const float* ca_wq = (const float*)d_in[7];
    const float* ca_wk = (const float*)d_in[8];
    const float* ca_wv = (const float*)d_in[9];
    const float* ca_wo = (const float*)d_in[10];
    const float* ca_bo = (const float*)d_in[11];
    const float* n1_g = (const float*)d_in[12];
    const float* n1_b = (const float*)d_in[13];
    const float* n2_g = (const float*)d_in[14];
    const float* n2_b = (const float*)d_in[15];
    const float* n3_g = (const float*)d_in[16];
    const float* n3_b = (const float*)d_in[17];
    const float* ff_w1 = (const float*)d_in[18];
    const float* ff_b1 = (const float*)d_in[19];
    const float* ff_w2 = (const float*)d_in[20];
    const float* ff_b2 = (const float*)d_in[21];

    size_t off = 0;
    auto alloc = [&](size_t bytes) {
        void* p = (char*)d_ws + off;
        off += (bytes + 255) & ~(size_t)255;
        return p;
    };
    __bf16* w_sa_qkvT = (__bf16*)alloc((size_t)3 * EMB * EMB * 2);
    __bf16* w_sa_oT   = (__bf16*)alloc((size_t)EMB * EMB * 2);
    __bf16* w_ca_qT   = (__bf16*)alloc((size_t)EMB * EMB * 2);
    __bf16* w_ca_kvT  = (__bf16*)alloc((size_t)2 * EMB * EMB * 2);
    __bf16* w_ca_oT   = (__bf16*)alloc((size_t)EMB * EMB * 2);
    __bf16* w1T       = (__bf16*)alloc((size_t)HIDN * EMB * 2);
    __bf16* w2T       = (__bf16*)alloc((size_t)EMB * HIDN * 2);
    __bf16* xb        = (__bf16*)alloc((size_t)MROWS * EMB * 2);   // xb, later cb
    __bf16* qkv       = (__bf16*)alloc((size_t)MROWS * 3 * EMB * 2); // qkv, later qx+kvc
    __bf16* ao        = (__bf16*)alloc((size_t)MROWS * EMB * 2);
    __bf16* hid       = (__bf16*)alloc((size_t)MROWS * HIDN * 2);
    __bf16* x1b       = (__bf16*)alloc((size_t)MROWS * EMB * 2);   // x1b, later x2b
    float* proj       = (float*)alloc((size_t)MROWS * EMB * 4);
    float* res1       = (float*)alloc((size_t)MROWS * EMB * 4);
    float* res2       = (float*)alloc((size_t)MROWS * EMB * 4);

    __bf16* qx  = qkv;
    __bf16* kvc = qkv + (size_t)MROWS * EMB;

    const float s4 = 0.17677669529663687f;  // 1024^-0.25
    dim3 tb(32, 8);
    dim3 t1k(32, 32);

    // weight transpose+cast
    transpose_cast_kernel<<<t1k, tb, 0, stream>>>(sa_wq, w_sa_qkvT, EMB, EMB);
    transpose_cast_kernel<<<t1k, tb, 0, stream>>>(sa_wk, w_sa_qkvT + (size_t)EMB * EMB, EMB, EMB);
    transpose_cast_kernel<<<t1k, tb, 0, stream>>>(sa_wv, w_sa_qkvT + (size_t)2 * EMB * EMB, EMB, EMB);
    transpose_cast_kernel<<<t1k, tb, 0, stream>>>(sa_wo, w_sa_oT, EMB, EMB);
    transpose_cast_kernel<<<t1k, tb, 0, stream>>>(ca_wq, w_ca_qT, EMB, EMB);
    transpose_cast_kernel<<<t1k, tb, 0, stream>>>(ca_wk, w_ca_kvT, EMB, EMB);
    transpose_cast_kernel<<<t1k, tb, 0, stream>>>(ca_wv, w_ca_kvT + (size_t)EMB * EMB, EMB, EMB);
    transpose_cast_kernel<<<t1k, tb, 0, stream>>>(ca_wo, w_ca_oT, EMB, EMB);
    transpose_cast_kernel<<<dim3(128, 32), tb, 0, stream>>>(ff_w1, w1T, EMB, HIDN);
    transpose_cast_kernel<<<dim3(32, 128), tb, 0, stream>>>(ff_w2, w2T, HIDN, EMB);

    // ---- self attention ----
    cast_bf16_kernel<<<4096, 256, 0, stream>>>(x, xb, MROWS * EMB);
    gemm_bt<1, 0><<<dim3(24, 32), 256, 0, stream>>>(xb, w_sa_qkvT, qkv, nullptr,
                                                    MROWS, 3 * EMB, EMB, s4, 1.f, 2048);
    attn_kernel<<<dim3(16, 16, 4), 256, 0, stream>>>(qkv, qkv + EMB, qkv + 2 * EMB,
                                                     3 * EMB, 3 * EMB, ao, 1, 1024);
    gemm_bt<0, 0><<<dim3(8, 32), 256, 0, stream>>>(ao, w_sa_oT, proj, sa_bo,
                                                   MROWS, EMB, EMB, 1.f, 1.f, 0);
    ln_kernel<<<4096, 256, 0, stream>>>(x, proj, n1_g, n1_b, res1, x1b);

    // ---- cross attention ----
    cast_bf16_kernel<<<4096, 256, 0, stream>>>(ctx, xb, MROWS * EMB);  // cb
    gemm_bt<1, 0><<<dim3(16, 32), 256, 0, stream>>>(xb, w_ca_kvT, kvc, nullptr,
                                                    MROWS, 2 * EMB, EMB, s4, 1.f, 1024);
    gemm_bt<1, 0><<<dim3(8, 32), 256, 0, stream>>>(x1b, w_ca_qT, qx, nullptr,
                                                   MROWS, EMB, EMB, s4, s4, 1 << 30);
    attn_kernel<<<dim3(16, 16, 4), 256, 0, stream>>>(qx, kvc, kvc + EMB,
                                                     EMB, 2 * EMB, ao, 0, 1024);
    gemm_bt<0, 0><<<dim3(8, 32), 256, 0, stream>>>(ao, w_ca_oT, proj, ca_bo,
                                                   MROWS, EMB, EMB, 1.f, 1.f, 0);
    ln_kernel<<<4096, 256, 0, stream>>>(res1, proj, n2_g, n2_b, res2, x1b);  // x2b

    // ---- FFN ----
    gemm_bt<1, 1><<<dim3(32, 32), 256, 0, stream>>>(x1b, w1T, hid, ff_b1,
                                                    MROWS, HIDN, EMB, 1.f, 1.f, 0);
    gemm_bt<0, 0><<<dim3(8, 32), 256, 0, stream>>>(hid, w2T, proj, ff_b2,
                                                   MROWS, EMB, HIDN, 1.f, 1.f, 0);
    ln_kernel<<<4096, 256, 0, stream>>>(res2, proj, n3_g, n3_b, (float*)d_out, nullptr);
}

// Round 2
// 566.183 us; speedup vs baseline: 1.1617x; 1.1617x over previous
//
#include <hip/hip_runtime.h>

typedef __bf16 bf16x8 __attribute__((ext_vector_type(8)));
typedef __bf16 bf16x4 __attribute__((ext_vector_type(4)));
typedef float floatx4 __attribute__((ext_vector_type(4)));

#define EMB 1024
#define MROWS 4096
#define HIDN 4096

// ---------------------------------------------------------------- helpers
__device__ __forceinline__ void load_lds16(const __bf16* g, __bf16* l) {
    __builtin_amdgcn_global_load_lds(
        (const __attribute__((address_space(1))) void*)g,
        (__attribute__((address_space(3))) void*)l, 16, 0, 0);
}

// ------------------------------------------------- fp32 -> bf16 transpose
// in: [R][C] fp32, out: [C][R] bf16
__global__ void transpose_cast_kernel(const float* __restrict__ in,
                                      __bf16* __restrict__ out, int R, int C) {
    __shared__ float tile[32][33];
    int tx = threadIdx.x, ty = threadIdx.y;
    int c0 = blockIdx.x * 32, r0 = blockIdx.y * 32;
#pragma unroll
    for (int i = 0; i < 32; i += 8)
        tile[ty + i][tx] = in[(size_t)(r0 + ty + i) * C + c0 + tx];
    __syncthreads();
#pragma unroll
    for (int i = 0; i < 32; i += 8)
        out[(size_t)(c0 + ty + i) * R + r0 + tx] = (__bf16)tile[tx][ty + i];
}

// --------------------------------------- bf16 V transpose (per batch-head)
// in: [b*Tc + t][ld] with head h at col h*64; out vt: [(b*16+h)*64 + s][Tc]
__global__ void transpose_v_kernel(const __bf16* __restrict__ in,
                                   __bf16* __restrict__ vt, int ld, int Tc) {
    __shared__ __bf16 tile[32][33];
    int tx = threadIdx.x, ty = threadIdx.y;
    int t0 = blockIdx.x * 32, s0 = blockIdx.y * 32;
    int bh = blockIdx.z, b = bh >> 4, h = bh & 15;
#pragma unroll
    for (int i = 0; i < 32; i += 8)
        tile[ty + i][tx] = in[(size_t)(b * Tc + t0 + ty + i) * ld + h * 64 + s0 + tx];
    __syncthreads();
#pragma unroll
    for (int i = 0; i < 32; i += 8)
        vt[((size_t)bh * 64 + s0 + ty + i) * Tc + t0 + tx] = tile[tx][ty + i];
}

// ------------------------------------------------------ fp32 -> bf16 cast
__global__ void cast_bf16_kernel(const float* __restrict__ in,
                                 __bf16* __restrict__ out, int n) {
    int i = (blockIdx.x * 256 + threadIdx.x) * 4;
    if (i >= n) return;
    float4 v = *(const float4*)(in + i);
    bf16x4 o;
    o[0] = (__bf16)v.x; o[1] = (__bf16)v.y; o[2] = (__bf16)v.z; o[3] = (__bf16)v.w;
    *(bf16x4*)(out + i) = o;
}

// ------------------------------------------------------------- GEMM (NT)
template <int STORE_BF16, int RELU>
__launch_bounds__(256, 2)
__global__ void gemm_bt(const __bf16* __restrict__ A, const __bf16* __restrict__ Bt,
                        void* __restrict__ Cv, const float* __restrict__ bias,
                        int M, int N, int Kd, float scale0, float scale1, int split) {
    __shared__ alignas(16) __bf16 As[128 * 32];
    __shared__ alignas(16) __bf16 Bs[128 * 32];
    int tid  = threadIdx.x;
    int wv   = tid >> 6, lane = tid & 63;
    int bn   = blockIdx.x * 128, bm = blockIdx.y * 128;
    int wm   = (wv & 1) * 64, wn = (wv >> 1) * 64;
    int l16  = lane & 15, g16 = lane >> 4;

    const __bf16* ag0 = A  + (size_t)(bm + (tid >> 2)) * Kd + (tid & 3) * 8;
    const __bf16* ag1 = ag0 + (size_t)64 * Kd;
    const __bf16* bg0 = Bt + (size_t)(bn + (tid >> 2)) * Kd + (tid & 3) * 8;
    const __bf16* bg1 = bg0 + (size_t)64 * Kd;
    __bf16* al0 = &As[tid * 8];
    __bf16* al1 = &As[2048 + tid * 8];
    __bf16* bl0 = &Bs[tid * 8];
    __bf16* bl1 = &Bs[2048 + tid * 8];

    floatx4 acc[4][4] = {};

    for (int k0 = 0; k0 < Kd; k0 += 32) {
        __syncthreads();
        load_lds16(ag0, al0); load_lds16(ag1, al1);
        load_lds16(bg0, bl0); load_lds16(bg1, bl1);
        ag0 += 32; ag1 += 32; bg0 += 32; bg1 += 32;
        __syncthreads();
        bf16x8 af[4], bfr[4];
#pragma unroll
        for (int i = 0; i < 4; ++i)
            af[i] = *(const bf16x8*)&As[(wm + i * 16 + l16) * 32 + g16 * 8];
#pragma unroll
        for (int j = 0; j < 4; ++j)
            bfr[j] = *(const bf16x8*)&Bs[(wn + j * 16 + l16) * 32 + g16 * 8];
#pragma unroll
        for (int i = 0; i < 4; ++i)
#pragma unroll
            for (int j = 0; j < 4; ++j)
                acc[i][j] = __builtin_amdgcn_mfma_f32_16x16x32_bf16(af[i], bfr[j], acc[i][j], 0, 0, 0);
    }

#pragma unroll
    for (int j = 0; j < 4; ++j) {
        int col  = bn + wn + j * 16 + l16;
        float sc = (col < split) ? scale0 : scale1;
        float bv = bias ? bias[col] : 0.f;
#pragma unroll
        for (int i = 0; i < 4; ++i) {
            int row0 = bm + wm + i * 16 + g16 * 4;
#pragma unroll
            for (int r = 0; r < 4; ++r) {
                float v = acc[i][j][r] * sc + bv;
                if (RELU) v = fmaxf(v, 0.f);
                size_t idx = (size_t)(row0 + r) * N + col;
                if (STORE_BF16) ((__bf16*)Cv)[idx] = (__bf16)v;
                else            ((float*)Cv)[idx]  = v;
            }
        }
    }
}

// ------------------------------------------------------- flash attention
// Computes S^T = K·Q^T per tile so each lane owns ONE q-row (q = lane&15):
// softmax reductions are 15 local ops + 2 shuffles. O accumulated transposed
// (A=V^T, B=P) so alpha-rescale and 1/l are lane-local. V pre-transposed in
// global: vt[(b*16+h)*64 + s][Tc]. qt swizzled so each CU gets mixed causal
// workloads (stride-256 dispatch preserves blockIdx.x otherwise).
__launch_bounds__(256, 4)
__global__ void attn_kernel(const __bf16* __restrict__ qb, const __bf16* __restrict__ kb,
                            const __bf16* __restrict__ vt, int ldq, int ldk,
                            __bf16* __restrict__ out, int causal, int Tc) {
    constexpr int T = 1024;
    __shared__ alignas(16) __bf16 Qs[64 * 72];
    __shared__ alignas(16) __bf16 Ks[64 * 72];
    __shared__ alignas(16) __bf16 Vs[64 * 72];
    __shared__ alignas(16) __bf16 Ps[4][16 * 72];

    int tid = threadIdx.x;
    int wv = tid >> 6, lane = tid & 63;
    int qt = (blockIdx.x + 4 * blockIdx.z) & 15;   // balance causal work per CU
    int h = blockIdx.y, b = blockIdx.z;
    int l16 = lane & 15, g16 = lane >> 4;

    // stage Q tile (64 rows x 64 dims), padded stride 72
#pragma unroll
    for (int cc = 0; cc < 2; ++cc) {
        int c = tid + cc * 256;
        int r = c >> 3, s8 = (c & 7) * 8;
        bf16x8 qv = *(const bf16x8*)(qb + (size_t)(b * T + qt * 64 + r) * ldq + h * 64 + s8);
        *(bf16x8*)&Qs[r * 72 + s8] = qv;
    }

    floatx4 oacc[4] = {};           // O^T: rows s (4 tiles), col q = l16
    float mi = -1e30f, li = 0.f;    // per-lane row q = l16

    int ktmax = causal ? (qt + 1) : (Tc / 64);
    for (int kt = 0; kt < ktmax; ++kt) {
        __syncthreads();
        // stage K rows [key][dim] and V^T rows [s][key] (both vector copies)
#pragma unroll
        for (int cc = 0; cc < 2; ++cc) {
            int c = tid + cc * 256;
            int r = c >> 3, s8 = (c & 7) * 8;
            bf16x8 kv8 = *(const bf16x8*)(kb + (size_t)(b * Tc + kt * 64 + r) * ldk + h * 64 + s8);
            *(bf16x8*)&Ks[r * 72 + s8] = kv8;
            bf16x8 vv8 = *(const bf16x8*)(vt + ((size_t)(b * 16 + h) * 64 + r) * Tc + kt * 64 + s8);
            *(bf16x8*)&Vs[r * 72 + s8] = vv8;
        }
        __syncthreads();

        // S^T[key=j*16+g16*4+r][q=l16] = mfma(K-frag, Q-frag)
        floatx4 sacc[4] = {};
#pragma unroll
        for (int kk = 0; kk < 2; ++kk) {
            bf16x8 bq = *(const bf16x8*)&Qs[(wv * 16 + l16) * 72 + kk * 32 + g16 * 8];
#pragma unroll
            for (int j = 0; j < 4; ++j) {
                bf16x8 ak = *(const bf16x8*)&Ks[(j * 16 + l16) * 72 + kk * 32 + g16 * 8];
                sacc[j] = __builtin_amdgcn_mfma_f32_16x16x32_bf16(ak, bq, sacc[j], 0, 0, 0);
            }
        }
        if (causal && kt == qt) {
            int qloc = wv * 16 + l16;
#pragma unroll
            for (int j = 0; j < 4; ++j)
#pragma unroll
                for (int r = 0; r < 4; ++r)
                    if (j * 16 + g16 * 4 + r > qloc) sacc[j][r] = -1e30f;
        }

        // online softmax: lane owns row q=l16 with 16 key-values
        float mt = -1e30f;
#pragma unroll
        for (int j = 0; j < 4; ++j)
#pragma unroll
            for (int r = 0; r < 4; ++r) mt = fmaxf(mt, sacc[j][r]);
        mt = fmaxf(mt, __shfl_xor(mt, 16));
        mt = fmaxf(mt, __shfl_xor(mt, 32));
        float mnew  = fmaxf(mi, mt);
        float alpha = __expf(mi - mnew);
        mi = mnew;
        float ls = 0.f;
#pragma unroll
        for (int j = 0; j < 4; ++j) {
            bf16x4 pk;
#pragma unroll
            for (int r = 0; r < 4; ++r) {
                float p = __expf(sacc[j][r] - mnew);
                ls += p;
                pk[r] = (__bf16)p;
            }
            // P[q=l16][key=j*16+g16*4 .. +3] packed write (8B)
            *(bf16x4*)&Ps[wv][l16 * 72 + j * 16 + g16 * 4] = pk;
        }
        ls += __shfl_xor(ls, 16);
        ls += __shfl_xor(ls, 32);
        li = li * alpha + ls;
#pragma unroll
        for (int j = 0; j < 4; ++j) {
            oacc[j][0] *= alpha; oacc[j][1] *= alpha;
            oacc[j][2] *= alpha; oacc[j][3] *= alpha;
        }
        // O^T[s][q] += mfma(V-frag[s][key], P-frag[q][key]) — Ps is wave-private,
        // no barrier needed (compiler inserts lgkmcnt).
#pragma unroll
        for (int kk = 0; kk < 2; ++kk) {
            bf16x8 bp = *(const bf16x8*)&Ps[wv][l16 * 72 + kk * 32 + g16 * 8];
#pragma unroll
            for (int j = 0; j < 4; ++j) {
                bf16x8 av = *(const bf16x8*)&Vs[(j * 16 + l16) * 72 + kk * 32 + g16 * 8];
                oacc[j] = __builtin_amdgcn_mfma_f32_16x16x32_bf16(av, bp, oacc[j], 0, 0, 0);
            }
        }
    }

    // transpose O^T -> O through LDS (reuse Ks), then coalesced vector stores
    __syncthreads();
    float inv = 1.f / li;
#pragma unroll
    for (int j = 0; j < 4; ++j) {
        bf16x4 ok;
#pragma unroll
        for (int r = 0; r < 4; ++r) ok[r] = (__bf16)(oacc[j][r] * inv);
        *(bf16x4*)&Ks[(wv * 16 + l16) * 72 + j * 16 + g16 * 4] = ok;
    }
    int rr = lane >> 2, c4 = (lane & 3) * 16;
    bf16x8 o0 = *(const bf16x8*)&Ks[(wv * 16 + rr) * 72 + c4];
    bf16x8 o1 = *(const bf16x8*)&Ks[(wv * 16 + rr) * 72 + c4 + 8];
    size_t ob = (size_t)(b * T + qt * 64 + wv * 16 + rr) * EMB + h * 64 + c4;
    *(bf16x8*)&out[ob]     = o0;
    *(bf16x8*)&out[ob + 8] = o1;
}

// ------------------------------------------------- residual + layernorm
__launch_bounds__(256)
__global__ void ln_kernel(const float* __restrict__ A, const float* __restrict__ Bv,
                          const float* __restrict__ g, const float* __restrict__ be,
                          float* __restrict__ outf, __bf16* __restrict__ outb) {
    __shared__ float red[8];
    int row = blockIdx.x, tid = threadIdx.x;
    const float4* a4 = (const float4*)(A + (size_t)row * EMB);
    const float4* b4 = (const float4*)(Bv + (size_t)row * EMB);
    float4 v = a4[tid], u = b4[tid];
    v.x += u.x; v.y += u.y; v.z += u.z; v.w += u.w;
    float s  = v.x + v.y + v.z + v.w;
    float ss = v.x * v.x + v.y * v.y + v.z * v.z + v.w * v.w;
#pragma unroll
    for (int o = 1; o < 64; o <<= 1) { s += __shfl_xor(s, o); ss += __shfl_xor(ss, o); }
    if ((tid & 63) == 0) { red[(tid >> 6) * 2] = s; red[(tid >> 6) * 2 + 1] = ss; }
    __syncthreads();
    s  = red[0] + red[2] + red[4] + red[6];
    ss = red[1] + red[3] + red[5] + red[7];
    float mu  = s * (1.0f / 1024.0f);
    float var = ss * (1.0f / 1024.0f) - mu * mu;
    float rs  = rsqrtf(var + 1e-5f);
    float4 gg = ((const float4*)g)[tid];
    float4 bb = ((const float4*)be)[tid];
    float4 y;
    y.x = (v.x - mu) * rs * gg.x + bb.x;
    y.y = (v.y - mu) * rs * gg.y + bb.y;
    y.z = (v.z - mu) * rs * gg.z + bb.z;
    y.w = (v.w - mu) * rs * gg.w + bb.w;
    ((float4*)(outf + (size_t)row * EMB))[tid] = y;
    if (outb) {
        bf16x4 o;
        o[0] = (__bf16)y.x; o[1] = (__bf16)y.y; o[2] = (__bf16)y.z; o[3] = (__bf16)y.w;
        *(bf16x4*)(outb + (size_t)row * EMB + tid * 4) = o;
    }
}

// ---------------------------------------------------------------- launch
extern "C" void kernel_launch(void* const* d_in, const int* in_sizes, int n_in,
                              void* d_out, int out_size, void* d_ws, size_t ws_size,
                              hipStream_t stream) {
    const float* x     = (const float*)d_in[0];
    const float* ctx   = (const float*)d_in[1];
    const float* sa_wq = (const float*)d_in[2];
    const float* sa_wk = (const float*)d_in[3];
    const float* sa_wv = (const float*)d_in[4];
    const float* sa_wo = (const float*)d_in[5];
    const float* sa_bo = (const float*)d_in[6];
    const float* ca_wq = (const float*)d_in[7];
    const float* ca_wk = (const float*)d_in[8];
    const float* ca_wv = (const float*)d_in[9];
    const float* ca_wo = (const float*)d_in[10];
    const float* ca_bo = (const float*)d_in[11];
    const float* n1_g = (const float*)d_in[12];
    const float* n1_b = (const float*)d_in[13];
    const float* n2_g = (const float*)d_in[14];
    const float* n2_b = (const float*)d_in[15];
    const float* n3_g = (const float*)d_in[16];
    const float* n3_b = (const float*)d_in[17];
    const float* ff_w1 = (const float*)d_in[18];
    const float* ff_b1 = (const float*)d_in[19];
    const float* ff_w2 = (const float*)d_in[20];
    const float* ff_b2 = (const float*)d_in[21];

    size_t off = 0;
    auto alloc = [&](size_t bytes) {
        void* p = (char*)d_ws + off;
        off += (bytes + 255) & ~(size_t)255;
        return p;
    };
    __bf16* w_sa_qkvT = (__bf16*)alloc((size_t)3 * EMB * EMB * 2);
    __bf16* w_sa_oT   = (__bf16*)alloc((size_t)EMB * EMB * 2);
    __bf16* w_ca_qT   = (__bf16*)alloc((size_t)EMB * EMB * 2);
    __bf16* w_ca_kvT  = (__bf16*)alloc((size_t)2 * EMB * EMB * 2);
    __bf16* w_ca_oT   = (__bf16*)alloc((size_t)EMB * EMB * 2);
    __bf16* w1T       = (__bf16*)alloc((size_t)HIDN * EMB * 2);
    __bf16* w2T       = (__bf16*)alloc((size_t)EMB * HIDN * 2);
    __bf16* xb        = (__bf16*)alloc((size_t)MROWS * EMB * 2);   // xb, later cb
    __bf16* qkv       = (__bf16*)alloc((size_t)MROWS * 3 * EMB * 2); // qkv, later qx+kvc
    __bf16* ao        = (__bf16*)alloc((size_t)MROWS * EMB * 2);
    __bf16* hid       = (__bf16*)alloc((size_t)MROWS * HIDN * 2);
    __bf16* x1b       = (__bf16*)alloc((size_t)MROWS * EMB * 2);   // x1b, later x2b
    float* proj       = (float*)alloc((size_t)MROWS * EMB * 4);
    float* res1       = (float*)alloc((size_t)MROWS * EMB * 4);
    float* res2       = (float*)alloc((size_t)MROWS * EMB * 4);

    __bf16* qx  = qkv;
    __bf16* kvc = qkv + (size_t)MROWS * EMB;
    // vt aliases proj: vt lives [after QKV gemm, before O-proj gemm writes proj]
    __bf16* vt  = (__bf16*)proj;

    const float s4 = 0.17677669529663687f;  // 1024^-0.25
    dim3 tb(32, 8);
    dim3 t1k(32, 32);

    // weight transpose+cast
    transpose_cast_kernel<<<t1k, tb, 0, stream>>>(sa_wq, w_sa_qkvT, EMB, EMB);
    transpose_cast_kernel<<<t1k, tb, 0, stream>>>(sa_wk, w_sa_qkvT + (size_t)EMB * EMB, EMB, EMB);
    transpose_cast_kernel<<<t1k, tb, 0, stream>>>(sa_wv, w_sa_qkvT + (size_t)2 * EMB * EMB, EMB, EMB);
    transpose_cast_kernel<<<t1k, tb, 0, stream>>>(sa_wo, w_sa_oT, EMB, EMB);
    transpose_cast_kernel<<<t1k, tb, 0, stream>>>(ca_wq, w_ca_qT, EMB, EMB);
    transpose_cast_kernel<<<t1k, tb, 0, stream>>>(ca_wk, w_ca_kvT, EMB, EMB);
    transpose_cast_kernel<<<t1k, tb, 0, stream>>>(ca_wv, w_ca_kvT + (size_t)EMB * EMB, EMB, EMB);
    transpose_cast_kernel<<<t1k, tb, 0, stream>>>(ca_wo, w_ca_oT, EMB, EMB);
    transpose_cast_kernel<<<dim3(128, 32), tb, 0, stream>>>(ff_w1, w1T, EMB, HIDN);
    transpose_cast_kernel<<<dim3(32, 128), tb, 0, stream>>>(ff_w2, w2T, HIDN, EMB);

    // ---- self attention ----
    cast_bf16_kernel<<<4096, 256, 0, stream>>>(x, xb, MROWS * EMB);
    gemm_bt<1, 0><<<dim3(24, 32), 256, 0, stream>>>(xb, w_sa_qkvT, qkv, nullptr,
                                                    MROWS, 3 * EMB, EMB, s4, 1.f, 2048);
    transpose_v_kernel<<<dim3(32, 2, 64), tb, 0, stream>>>(qkv + 2 * EMB, vt, 3 * EMB, 1024);
    attn_kernel<<<dim3(16, 16, 4), 256, 0, stream>>>(qkv, qkv + EMB, vt,
                                                     3 * EMB, 3 * EMB, ao, 1, 1024);
    gemm_bt<0, 0><<<dim3(8, 32), 256, 0, stream>>>(ao, w_sa_oT, proj, sa_bo,
                                                   MROWS, EMB, EMB, 1.f, 1.f, 0);
    ln_kernel<<<4096, 256, 0, stream>>>(x, proj, n1_g, n1_b, res1, x1b);

    // ---- cross attention ----
    cast_bf16_kernel<<<4096, 256, 0, stream>>>(ctx, xb, MROWS * EMB);  // cb
    gemm_bt<1, 0><<<dim3(16, 32), 256, 0, stream>>>(xb, w_ca_kvT, kvc, nullptr,
                                                    MROWS, 2 * EMB, EMB, s4, 1.f, 1024);
    gemm_bt<1, 0><<<dim3(8, 32), 256, 0, stream>>>(x1b, w_ca_qT, qx, nullptr,
                                                   MROWS, EMB, EMB, s4, s4, 1 << 30);
    transpose_v_kernel<<<dim3(32, 2, 64), tb, 0, stream>>>(kvc + EMB, vt, 2 * EMB, 1024);
    attn_kernel<<<dim3(16, 16, 4), 256, 0, stream>>>(qx, kvc, vt,
                                                     EMB, 2 * EMB, ao, 0, 1024);
    gemm_bt<0, 0><<<dim3(8, 32), 256, 0, stream>>>(ao, w_ca_oT, proj, ca_bo,
                                                   MROWS, EMB, EMB, 1.f, 1.f, 0);
    ln_kernel<<<4096, 256, 0, stream>>>(res1, proj, n2_g, n2_b, res2, x1b);  // x2b

    // ---- FFN ----
    gemm_bt<1, 1><<<dim3(32, 32), 256, 0, stream>>>(x1b, w1T, hid, ff_b1,
                                                    MROWS, HIDN, EMB, 1.f, 1.f, 0);
    gemm_bt<0, 0><<<dim3(8, 32), 256, 0, stream>>>(hid, w2T, proj, ff_b2,
                                                   MROWS, EMB, HIDN, 1.f, 1.f, 0);
    ln_kernel<<<4096, 256, 0, stream>>>(res2, proj, n3_g, n3_b, (float*)d_out, nullptr);
}

// Round 3
// 531.859 us; speedup vs baseline: 1.2367x; 1.0645x over previous
//
#include <hip/hip_runtime.h>

typedef __bf16 bf16x8 __attribute__((ext_vector_type(8)));
typedef __bf16 bf16x4 __attribute__((ext_vector_type(4)));
typedef float floatx4 __attribute__((ext_vector_type(4)));

#define EMB 1024
#define MROWS 4096
#define HIDN 4096

// ---------------------------------------------------------------- helpers
__device__ __forceinline__ void load_lds16(const __bf16* g, __bf16* l) {
    __builtin_amdgcn_global_load_lds(
        (const __attribute__((address_space(1))) void*)g,
        (__attribute__((address_space(3))) void*)l, 16, 0, 0);
}

// ------------------------------------------------- fp32 -> bf16 transpose
// in: [R][C] fp32, out: [C][R] bf16
__global__ void transpose_cast_kernel(const float* __restrict__ in,
                                      __bf16* __restrict__ out, int R, int C) {
    __shared__ float tile[32][33];
    int tx = threadIdx.x, ty = threadIdx.y;
    int c0 = blockIdx.x * 32, r0 = blockIdx.y * 32;
#pragma unroll
    for (int i = 0; i < 32; i += 8)
        tile[ty + i][tx] = in[(size_t)(r0 + ty + i) * C + c0 + tx];
    __syncthreads();
#pragma unroll
    for (int i = 0; i < 32; i += 8)
        out[(size_t)(c0 + ty + i) * R + r0 + tx] = (__bf16)tile[tx][ty + i];
}

// --------------------------- batched 1024x1024 transposes (one dispatch)
struct TC8 { const float* s[8]; __bf16* d[8]; };
__global__ void transpose_cast8_kernel(TC8 a) {
    __shared__ float tile[32][33];
    const float* in = a.s[blockIdx.z];
    __bf16* out = a.d[blockIdx.z];
    int tx = threadIdx.x, ty = threadIdx.y;
    int c0 = blockIdx.x * 32, r0 = blockIdx.y * 32;
#pragma unroll
    for (int i = 0; i < 32; i += 8)
        tile[ty + i][tx] = in[(size_t)(r0 + ty + i) * EMB + c0 + tx];
    __syncthreads();
#pragma unroll
    for (int i = 0; i < 32; i += 8)
        out[(size_t)(c0 + ty + i) * EMB + r0 + tx] = (__bf16)tile[tx][ty + i];
}

// --------------------------------------- bf16 V transpose (per batch-head)
// in: [b*Tc + t][ld] with head h at col h*64; out vt: [(b*16+h)*64 + s][Tc]
__global__ void transpose_v_kernel(const __bf16* __restrict__ in,
                                   __bf16* __restrict__ vt, int ld, int Tc) {
    __shared__ __bf16 tile[32][33];
    int tx = threadIdx.x, ty = threadIdx.y;
    int t0 = blockIdx.x * 32, s0 = blockIdx.y * 32;
    int bh = blockIdx.z, b = bh >> 4, h = bh & 15;
#pragma unroll
    for (int i = 0; i < 32; i += 8)
        tile[ty + i][tx] = in[(size_t)(b * Tc + t0 + ty + i) * ld + h * 64 + s0 + tx];
    __syncthreads();
#pragma unroll
    for (int i = 0; i < 32; i += 8)
        vt[((size_t)bh * 64 + s0 + ty + i) * Tc + t0 + tx] = tile[tx][ty + i];
}

// ------------------------------------------------------ fp32 -> bf16 cast
__global__ void cast_bf16_kernel(const float* __restrict__ in,
                                 __bf16* __restrict__ out, int n) {
    int i = (blockIdx.x * 256 + threadIdx.x) * 4;
    if (i >= n) return;
    float4 v = *(const float4*)(in + i);
    bf16x4 o;
    o[0] = (__bf16)v.x; o[1] = (__bf16)v.y; o[2] = (__bf16)v.z; o[3] = (__bf16)v.w;
    *(bf16x4*)(out + i) = o;
}

// ------------------------------------------------------------- GEMM (NT)
// C[M][N] = A[M][K] * Bt[N][K]^T, bf16 in, fp32 accum. Split-K via gridDim.z:
// slice z covers K-chunk [z*kc, (z+1)*kc); fp32 slices go to c0..c3 (bias only
// in slice 0; downstream ln_kernel sums them). grid.z==1 + STORE_BF16 stores
// bf16 to cb. launch_bounds(256,4): 4 blocks/CU (56 VGPR + 64 AGPR fits 128).
template <int STORE_BF16, int RELU>
__launch_bounds__(256, 4)
__global__ void gemm_bt(const __bf16* __restrict__ A, const __bf16* __restrict__ Bt,
                        float* __restrict__ c0, float* __restrict__ c1,
                        float* __restrict__ c2, float* __restrict__ c3,
                        __bf16* __restrict__ cb, const float* __restrict__ bias,
                        int M, int N, int Kd, float scale0, float scale1, int split) {
    __shared__ alignas(16) __bf16 As[128 * 32];
    __shared__ alignas(16) __bf16 Bs[128 * 32];
    int tid  = threadIdx.x;
    int wv   = tid >> 6, lane = tid & 63;
    int bn   = blockIdx.x * 128, bm = blockIdx.y * 128;
    int wm   = (wv & 1) * 64, wn = (wv >> 1) * 64;
    int l16  = lane & 15, g16 = lane >> 4;

    int kc   = Kd / gridDim.z;          // K-chunk for this slice
    int zoff = blockIdx.z * kc;

    const __bf16* ag0 = A  + (size_t)(bm + (tid >> 2)) * Kd + zoff + (tid & 3) * 8;
    const __bf16* ag1 = ag0 + (size_t)64 * Kd;
    const __bf16* bg0 = Bt + (size_t)(bn + (tid >> 2)) * Kd + zoff + (tid & 3) * 8;
    const __bf16* bg1 = bg0 + (size_t)64 * Kd;
    __bf16* al0 = &As[tid * 8];
    __bf16* al1 = &As[2048 + tid * 8];
    __bf16* bl0 = &Bs[tid * 8];
    __bf16* bl1 = &Bs[2048 + tid * 8];

    floatx4 acc[4][4] = {};

    for (int k0 = 0; k0 < kc; k0 += 32) {
        __syncthreads();
        load_lds16(ag0, al0); load_lds16(ag1, al1);
        load_lds16(bg0, bl0); load_lds16(bg1, bl1);
        ag0 += 32; ag1 += 32; bg0 += 32; bg1 += 32;
        __syncthreads();
        bf16x8 af[4], bfr[4];
#pragma unroll
        for (int i = 0; i < 4; ++i)
            af[i] = *(const bf16x8*)&As[(wm + i * 16 + l16) * 32 + g16 * 8];
#pragma unroll
        for (int j = 0; j < 4; ++j)
            bfr[j] = *(const bf16x8*)&Bs[(wn + j * 16 + l16) * 32 + g16 * 8];
#pragma unroll
        for (int i = 0; i < 4; ++i)
#pragma unroll
            for (int j = 0; j < 4; ++j)
                acc[i][j] = __builtin_amdgcn_mfma_f32_16x16x32_bf16(af[i], bfr[j], acc[i][j], 0, 0, 0);
    }

    float* Cp = (blockIdx.z == 0) ? c0 : (blockIdx.z == 1) ? c1
              : (blockIdx.z == 2) ? c2 : c3;
    const float* bz = (blockIdx.z == 0) ? bias : nullptr;

#pragma unroll
    for (int j = 0; j < 4; ++j) {
        int col  = bn + wn + j * 16 + l16;
        float sc = (col < split) ? scale0 : scale1;
        float bv = bz ? bz[col] : 0.f;
#pragma unroll
        for (int i = 0; i < 4; ++i) {
            int row0 = bm + wm + i * 16 + g16 * 4;
#pragma unroll
            for (int r = 0; r < 4; ++r) {
                float v = acc[i][j][r] * sc + bv;
                if (RELU) v = fmaxf(v, 0.f);
                size_t idx = (size_t)(row0 + r) * N + col;
                if (STORE_BF16) cb[idx] = (__bf16)v;
                else            Cp[idx] = v;
            }
        }
    }
}

// ------------------------------------------------------- flash attention
// S^T = K·Q^T per tile so each lane owns ONE q-row (q = lane&15): softmax is
// 15 local ops + 2 shuffles. O accumulated transposed (A=V^T, B=P) so the
// alpha-rescale and 1/l are lane-local. V pre-transposed in global.
__launch_bounds__(256, 4)
__global__ void attn_kernel(const __bf16* __restrict__ qb, const __bf16* __restrict__ kb,
                            const __bf16* __restrict__ vt, int ldq, int ldk,
                            __bf16* __restrict__ out, int causal, int Tc) {
    constexpr int T = 1024;
    __shared__ alignas(16) __bf16 Qs[64 * 72];
    __shared__ alignas(16) __bf16 Ks[64 * 72];
    __shared__ alignas(16) __bf16 Vs[64 * 72];
    __shared__ alignas(16) __bf16 Ps[4][16 * 72];

    int tid = threadIdx.x;
    int wv = tid >> 6, lane = tid & 63;
    int qt = (blockIdx.x + 4 * blockIdx.z) & 15;   // balance causal work per CU
    int h = blockIdx.y, b = blockIdx.z;
    int l16 = lane & 15, g16 = lane >> 4;

#pragma unroll
    for (int cc = 0; cc < 2; ++cc) {
        int c = tid + cc * 256;
        int r = c >> 3, s8 = (c & 7) * 8;
        bf16x8 qv = *(const bf16x8*)(qb + (size_t)(b * T + qt * 64 + r) * ldq + h * 64 + s8);
        *(bf16x8*)&Qs[r * 72 + s8] = qv;
    }

    floatx4 oacc[4] = {};
    float mi = -1e30f, li = 0.f;

    int ktmax = causal ? (qt + 1) : (Tc / 64);
    for (int kt = 0; kt < ktmax; ++kt) {
        __syncthreads();
#pragma unroll
        for (int cc = 0; cc < 2; ++cc) {
            int c = tid + cc * 256;
            int r = c >> 3, s8 = (c & 7) * 8;
            bf16x8 kv8 = *(const bf16x8*)(kb + (size_t)(b * Tc + kt * 64 + r) * ldk + h * 64 + s8);
            *(bf16x8*)&Ks[r * 72 + s8] = kv8;
            bf16x8 vv8 = *(const bf16x8*)(vt + ((size_t)(b * 16 + h) * 64 + r) * Tc + kt * 64 + s8);
            *(bf16x8*)&Vs[r * 72 + s8] = vv8;
        }
        __syncthreads();

        floatx4 sacc[4] = {};
#pragma unroll
        for (int kk = 0; kk < 2; ++kk) {
            bf16x8 bq = *(const bf16x8*)&Qs[(wv * 16 + l16) * 72 + kk * 32 + g16 * 8];
#pragma unroll
            for (int j = 0; j < 4; ++j) {
                bf16x8 ak = *(const bf16x8*)&Ks[(j * 16 + l16) * 72 + kk * 32 + g16 * 8];
                sacc[j] = __builtin_amdgcn_mfma_f32_16x16x32_bf16(ak, bq, sacc[j], 0, 0, 0);
            }
        }
        if (causal && kt == qt) {
            int qloc = wv * 16 + l16;
#pragma unroll
            for (int j = 0; j < 4; ++j)
#pragma unroll
                for (int r = 0; r < 4; ++r)
                    if (j * 16 + g16 * 4 + r > qloc) sacc[j][r] = -1e30f;
        }

        float mt = -1e30f;
#pragma unroll
        for (int j = 0; j < 4; ++j)
#pragma unroll
            for (int r = 0; r < 4; ++r) mt = fmaxf(mt, sacc[j][r]);
        mt = fmaxf(mt, __shfl_xor(mt, 16));
        mt = fmaxf(mt, __shfl_xor(mt, 32));
        float mnew  = fmaxf(mi, mt);
        float alpha = __expf(mi - mnew);
        mi = mnew;
        float ls = 0.f;
#pragma unroll
        for (int j = 0; j < 4; ++j) {
            bf16x4 pk;
#pragma unroll
            for (int r = 0; r < 4; ++r) {
                float p = __expf(sacc[j][r] - mnew);
                ls += p;
                pk[r] = (__bf16)p;
            }
            *(bf16x4*)&Ps[wv][l16 * 72 + j * 16 + g16 * 4] = pk;
        }
        ls += __shfl_xor(ls, 16);
        ls += __shfl_xor(ls, 32);
        li = li * alpha + ls;
#pragma unroll
        for (int j = 0; j < 4; ++j) {
            oacc[j][0] *= alpha; oacc[j][1] *= alpha;
            oacc[j][2] *= alpha; oacc[j][3] *= alpha;
        }
#pragma unroll
        for (int kk = 0; kk < 2; ++kk) {
            bf16x8 bp = *(const bf16x8*)&Ps[wv][l16 * 72 + kk * 32 + g16 * 8];
#pragma unroll
            for (int j = 0; j < 4; ++j) {
                bf16x8 av = *(const bf16x8*)&Vs[(j * 16 + l16) * 72 + kk * 32 + g16 * 8];
                oacc[j] = __builtin_amdgcn_mfma_f32_16x16x32_bf16(av, bp, oacc[j], 0, 0, 0);
            }
        }
    }

    __syncthreads();
    float inv = 1.f / li;
#pragma unroll
    for (int j = 0; j < 4; ++j) {
        bf16x4 ok;
#pragma unroll
        for (int r = 0; r < 4; ++r) ok[r] = (__bf16)(oacc[j][r] * inv);
        *(bf16x4*)&Ks[(wv * 16 + l16) * 72 + j * 16 + g16 * 4] = ok;
    }
    int rr = lane >> 2, c4 = (lane & 3) * 16;
    bf16x8 o0 = *(const bf16x8*)&Ks[(wv * 16 + rr) * 72 + c4];
    bf16x8 o1 = *(const bf16x8*)&Ks[(wv * 16 + rr) * 72 + c4 + 8];
    size_t ob = (size_t)(b * T + qt * 64 + wv * 16 + rr) * EMB + h * 64 + c4;
    *(bf16x8*)&out[ob]     = o0;
    *(bf16x8*)&out[ob + 8] = o1;
}

// --------------------------------- residual + split-K partials + layernorm
// y = LN(res + p0 + p1 [+ p2 + p3]) * g + b; fp32 out + optional bf16 out
__launch_bounds__(256)
__global__ void ln_kernel(const float* __restrict__ res,
                          const float* __restrict__ p0, const float* __restrict__ p1,
                          const float* __restrict__ p2, const float* __restrict__ p3,
                          const float* __restrict__ g, const float* __restrict__ be,
                          float* __restrict__ outf, __bf16* __restrict__ outb) {
    __shared__ float red[8];
    int row = blockIdx.x, tid = threadIdx.x;
    size_t base = (size_t)row * EMB;
    float4 v = ((const float4*)(res + base))[tid];
    float4 u0 = ((const float4*)(p0 + base))[tid];
    float4 u1 = ((const float4*)(p1 + base))[tid];
    v.x += u0.x + u1.x; v.y += u0.y + u1.y;
    v.z += u0.z + u1.z; v.w += u0.w + u1.w;
    if (p2) {
        float4 u2 = ((const float4*)(p2 + base))[tid];
        float4 u3 = ((const float4*)(p3 + base))[tid];
        v.x += u2.x + u3.x; v.y += u2.y + u3.y;
        v.z += u2.z + u3.z; v.w += u2.w + u3.w;
    }
    float s  = v.x + v.y + v.z + v.w;
    float ss = v.x * v.x + v.y * v.y + v.z * v.z + v.w * v.w;
#pragma unroll
    for (int o = 1; o < 64; o <<= 1) { s += __shfl_xor(s, o); ss += __shfl_xor(ss, o); }
    if ((tid & 63) == 0) { red[(tid >> 6) * 2] = s; red[(tid >> 6) * 2 + 1] = ss; }
    __syncthreads();
    s  = red[0] + red[2] + red[4] + red[6];
    ss = red[1] + red[3] + red[5] + red[7];
    float mu  = s * (1.0f / 1024.0f);
    float var = ss * (1.0f / 1024.0f) - mu * mu;
    float rs  = rsqrtf(var + 1e-5f);
    float4 gg = ((const float4*)g)[tid];
    float4 bb = ((const float4*)be)[tid];
    float4 y;
    y.x = (v.x - mu) * rs * gg.x + bb.x;
    y.y = (v.y - mu) * rs * gg.y + bb.y;
    y.z = (v.z - mu) * rs * gg.z + bb.z;
    y.w = (v.w - mu) * rs * gg.w + bb.w;
    ((float4*)(outf + base))[tid] = y;
    if (outb) {
        bf16x4 o;
        o[0] = (__bf16)y.x; o[1] = (__bf16)y.y; o[2] = (__bf16)y.z; o[3] = (__bf16)y.w;
        *(bf16x4*)(outb + base + tid * 4) = o;
    }
}

// ---------------------------------------------------------------- launch
extern "C" void kernel_launch(void* const* d_in, const int* in_sizes, int n_in,
                              void* d_out, int out_size, void* d_ws, size_t ws_size,
                              hipStream_t stream) {
    const float* x     = (const float*)d_in[0];
    const float* ctx   = (const float*)d_in[1];
    const float* sa_wq = (const float*)d_in[2];
    const float* sa_wk = (const float*)d_in[3];
    const float* sa_wv = (const float*)d_in[4];
    const float* sa_wo = (const float*)d_in[5];
    const float* sa_bo = (const float*)d_in[6];
    const float* ca_wq = (const float*)d_in[7];
    const float* ca_wk = (const float*)d_in[8];
    const float* ca_wv = (const float*)d_in[9];
    const float* ca_wo = (const float*)d_in[10];
    const float* ca_bo = (const float*)d_in[11];
    const float* n1_g = (const float*)d_in[12];
    const float* n1_b = (const float*)d_in[13];
    const float* n2_g = (const float*)d_in[14];
    const float* n2_b = (const float*)d_in[15];
    const float* n3_g = (const float*)d_in[16];
    const float* n3_b = (const float*)d_in[17];
    const float* ff_w1 = (const float*)d_in[18];
    const float* ff_b1 = (const float*)d_in[19];
    const float* ff_w2 = (const float*)d_in[20];
    const float* ff_b2 = (const float*)d_in[21];

    size_t off = 0;
    auto alloc = [&](size_t bytes) {
        void* p = (char*)d_ws + off;
        off += (bytes + 255) & ~(size_t)255;
        return p;
    };
    __bf16* w_sa_qkvT = (__bf16*)alloc((size_t)3 * EMB * EMB * 2);
    __bf16* w_sa_oT   = (__bf16*)alloc((size_t)EMB * EMB * 2);
    __bf16* w_ca_qT   = (__bf16*)alloc((size_t)EMB * EMB * 2);
    __bf16* w_ca_kvT  = (__bf16*)alloc((size_t)2 * EMB * EMB * 2);
    __bf16* w_ca_oT   = (__bf16*)alloc((size_t)EMB * EMB * 2);
    __bf16* w1T       = (__bf16*)alloc((size_t)HIDN * EMB * 2);
    __bf16* w2T       = (__bf16*)alloc((size_t)EMB * HIDN * 2);
    __bf16* xb        = (__bf16*)alloc((size_t)MROWS * EMB * 2);     // 8 MB
    __bf16* qkv       = (__bf16*)alloc((size_t)MROWS * 3 * EMB * 2); // 24 MB (adj. to xb)
    __bf16* ao        = (__bf16*)alloc((size_t)MROWS * EMB * 2);
    __bf16* hid       = (__bf16*)alloc((size_t)MROWS * HIDN * 2);
    __bf16* x1b       = (__bf16*)alloc((size_t)MROWS * EMB * 2);
    float* proj       = (float*)alloc((size_t)MROWS * EMB * 4);
    float* res1       = (float*)alloc((size_t)MROWS * EMB * 4);
    float* res2       = (float*)alloc((size_t)MROWS * EMB * 4);

    __bf16* qx  = qkv;
    __bf16* kvc = qkv + (size_t)MROWS * EMB;
    // vt aliases proj (live only between V-producing GEMM and O-proj GEMM)
    __bf16* vt  = (__bf16*)proj;
    // split-K partial overlays (liveness-checked):
    // part1 spans xb + qkv[0:8MB] — dead at sa_o (attnSA done), ca_o (qx/cb
    // consumed), ff2 (all attn buffers dead). part2 = next 16 MB of qkv
    // (ff2 only). part3 = res1 (dead after ln2; ln3 reads res2 only).
    float* part1 = (float*)xb;
    float* part2 = (float*)((char*)xb + (size_t)16 * 1024 * 1024);
    float* part3 = res1;

    const float s4 = 0.17677669529663687f;  // 1024^-0.25
    dim3 tb(32, 8);

    // weight transpose+cast: 8 square ones in a single dispatch
    TC8 tc;
    tc.s[0] = sa_wq; tc.d[0] = w_sa_qkvT;
    tc.s[1] = sa_wk; tc.d[1] = w_sa_qkvT + (size_t)EMB * EMB;
    tc.s[2] = sa_wv; tc.d[2] = w_sa_qkvT + (size_t)2 * EMB * EMB;
    tc.s[3] = sa_wo; tc.d[3] = w_sa_oT;
    tc.s[4] = ca_wq; tc.d[4] = w_ca_qT;
    tc.s[5] = ca_wk; tc.d[5] = w_ca_kvT;
    tc.s[6] = ca_wv; tc.d[6] = w_ca_kvT + (size_t)EMB * EMB;
    tc.s[7] = ca_wo; tc.d[7] = w_ca_oT;
    transpose_cast8_kernel<<<dim3(32, 32, 8), tb, 0, stream>>>(tc);
    transpose_cast_kernel<<<dim3(128, 32), tb, 0, stream>>>(ff_w1, w1T, EMB, HIDN);
    transpose_cast_kernel<<<dim3(32, 128), tb, 0, stream>>>(ff_w2, w2T, HIDN, EMB);

    // ---- self attention ----
    cast_bf16_kernel<<<4096, 256, 0, stream>>>(x, xb, MROWS * EMB);
    gemm_bt<1, 0><<<dim3(24, 32), 256, 0, stream>>>(xb, w_sa_qkvT,
        nullptr, nullptr, nullptr, nullptr, qkv, nullptr,
        MROWS, 3 * EMB, EMB, s4, 1.f, 2048);
    transpose_v_kernel<<<dim3(32, 2, 64), tb, 0, stream>>>(qkv + 2 * EMB, vt, 3 * EMB, 1024);
    attn_kernel<<<dim3(16, 16, 4), 256, 0, stream>>>(qkv, qkv + EMB, vt,
                                                     3 * EMB, 3 * EMB, ao, 1, 1024);
    gemm_bt<0, 0><<<dim3(8, 32, 2), 256, 0, stream>>>(ao, w_sa_oT,
        proj, part1, nullptr, nullptr, nullptr, sa_bo,
        MROWS, EMB, EMB, 1.f, 1.f, 0);
    ln_kernel<<<4096, 256, 0, stream>>>(x, proj, part1, nullptr, nullptr,
                                        n1_g, n1_b, res1, x1b);

    // ---- cross attention ----
    cast_bf16_kernel<<<4096, 256, 0, stream>>>(ctx, xb, MROWS * EMB);  // cb
    gemm_bt<1, 0><<<dim3(16, 32), 256, 0, stream>>>(xb, w_ca_kvT,
        nullptr, nullptr, nullptr, nullptr, kvc, nullptr,
        MROWS, 2 * EMB, EMB, s4, 1.f, 1024);
    gemm_bt<1, 0><<<dim3(8, 32), 256, 0, stream>>>(x1b, w_ca_qT,
        nullptr, nullptr, nullptr, nullptr, qx, nullptr,
        MROWS, EMB, EMB, s4, s4, 1 << 30);
    transpose_v_kernel<<<dim3(32, 2, 64), tb, 0, stream>>>(kvc + EMB, vt, 2 * EMB, 1024);
    attn_kernel<<<dim3(16, 16, 4), 256, 0, stream>>>(qx, kvc, vt,
                                                     EMB, 2 * EMB, ao, 0, 1024);
    gemm_bt<0, 0><<<dim3(8, 32, 2), 256, 0, stream>>>(ao, w_ca_oT,
        proj, part1, nullptr, nullptr, nullptr, ca_bo,
        MROWS, EMB, EMB, 1.f, 1.f, 0);
    ln_kernel<<<4096, 256, 0, stream>>>(res1, proj, part1, nullptr, nullptr,
                                        n2_g, n2_b, res2, x1b);

    // ---- FFN ----
    gemm_bt<1, 1><<<dim3(32, 32), 256, 0, stream>>>(x1b, w1T,
        nullptr, nullptr, nullptr, nullptr, hid, ff_b1,
        MROWS, HIDN, EMB, 1.f, 1.f, 0);
    gemm_bt<0, 0><<<dim3(8, 32, 4), 256, 0, stream>>>(hid, w2T,
        proj, part1, part2, part3, nullptr, ff_b2,
        MROWS, EMB, HIDN, 1.f, 1.f, 0);
    ln_kernel<<<4096, 256, 0, stream>>>(res2, proj, part1, part2, part3,
                                        n3_g, n3_b, (float*)d_out, nullptr);
}

// Round 4
// 489.663 us; speedup vs baseline: 1.3433x; 1.0862x over previous
//
#include <hip/hip_runtime.h>

typedef __bf16 bf16x8 __attribute__((ext_vector_type(8)));
typedef __bf16 bf16x4 __attribute__((ext_vector_type(4)));
typedef float floatx4 __attribute__((ext_vector_type(4)));

#define EMB 1024
#define MROWS 4096
#define HIDN 4096
#define PSTRIDE ((size_t)MROWS * EMB)   // partial-slice stride (elements)

// ---------------------------------------------------------------- helpers
__device__ __forceinline__ void load_lds16(const __bf16* g, __bf16* l) {
    __builtin_amdgcn_global_load_lds(
        (const __attribute__((address_space(1))) void*)g,
        (__attribute__((address_space(3))) void*)l, 16, 0, 0);
}

// ------------------------------------------------- fp32 -> bf16 transpose
__global__ void transpose_cast_kernel(const float* __restrict__ in,
                                      __bf16* __restrict__ out, int R, int C) {
    __shared__ float tile[32][33];
    int tx = threadIdx.x, ty = threadIdx.y;
    int c0 = blockIdx.x * 32, r0 = blockIdx.y * 32;
#pragma unroll
    for (int i = 0; i < 32; i += 8)
        tile[ty + i][tx] = in[(size_t)(r0 + ty + i) * C + c0 + tx];
    __syncthreads();
#pragma unroll
    for (int i = 0; i < 32; i += 8)
        out[(size_t)(c0 + ty + i) * R + r0 + tx] = (__bf16)tile[tx][ty + i];
}

// --------------------------- batched 1024x1024 transposes (one dispatch)
struct TC8 { const float* s[8]; __bf16* d[8]; };
__global__ void transpose_cast8_kernel(TC8 a) {
    __shared__ float tile[32][33];
    const float* in = a.s[blockIdx.z];
    __bf16* out = a.d[blockIdx.z];
    int tx = threadIdx.x, ty = threadIdx.y;
    int c0 = blockIdx.x * 32, r0 = blockIdx.y * 32;
#pragma unroll
    for (int i = 0; i < 32; i += 8)
        tile[ty + i][tx] = in[(size_t)(r0 + ty + i) * EMB + c0 + tx];
    __syncthreads();
#pragma unroll
    for (int i = 0; i < 32; i += 8)
        out[(size_t)(c0 + ty + i) * EMB + r0 + tx] = (__bf16)tile[tx][ty + i];
}

// --------------------------------------- bf16 V transpose (per batch-head)
__global__ void transpose_v_kernel(const __bf16* __restrict__ in,
                                   __bf16* __restrict__ vt, int ld, int Tc) {
    __shared__ __bf16 tile[32][33];
    int tx = threadIdx.x, ty = threadIdx.y;
    int t0 = blockIdx.x * 32, s0 = blockIdx.y * 32;
    int bh = blockIdx.z, b = bh >> 4, h = bh & 15;
#pragma unroll
    for (int i = 0; i < 32; i += 8)
        tile[ty + i][tx] = in[(size_t)(b * Tc + t0 + ty + i) * ld + h * 64 + s0 + tx];
    __syncthreads();
#pragma unroll
    for (int i = 0; i < 32; i += 8)
        vt[((size_t)bh * 64 + s0 + ty + i) * Tc + t0 + tx] = tile[tx][ty + i];
}

// ------------------------------------------------------ fp32 -> bf16 cast
__global__ void cast_bf16_kernel(const float* __restrict__ in,
                                 __bf16* __restrict__ out, int n) {
    int i = (blockIdx.x * 256 + threadIdx.x) * 4;
    if (i >= n) return;
    float4 v = *(const float4*)(in + i);
    bf16x4 o;
    o[0] = (__bf16)v.x; o[1] = (__bf16)v.y; o[2] = (__bf16)v.z; o[3] = (__bf16)v.w;
    *(bf16x4*)(out + i) = o;
}

// ------------------------------------------------------------- GEMM (NT)
// C[M][N] = A[M][K] * Bt[N][K]^T, bf16 in/out, fp32 accum.
// XCD-aware swizzle: predicted xcd = linear_block_id % 8 (round-robin
// dispatch); work coords chosen so each XCD owns a (bm-band x bn-band x
// one z) working set: fx*fy*gridDim.z must equal 8.
// Split-K slices write bf16 partials: slice 0 -> cb, slice z>0 ->
// cbalt + (z-1)*M*N (bias only in slice 0; ln_kernel sums slices).
template <int RELU>
__launch_bounds__(256, 4)
__global__ void gemm_bt(const __bf16* __restrict__ A, const __bf16* __restrict__ Bt,
                        __bf16* __restrict__ cb, __bf16* __restrict__ cbalt,
                        const float* __restrict__ bias,
                        int M, int N, int Kd, float scale0, float scale1,
                        int split, int fx, int fy) {
    __shared__ alignas(16) __bf16 As[128 * 32];
    __shared__ alignas(16) __bf16 Bs[128 * 32];
    int tid  = threadIdx.x;
    int wv   = tid >> 6, lane = tid & 63;

    // ---- XCD swizzle ----
    int L   = blockIdx.x + gridDim.x * (blockIdx.y + gridDim.y * blockIdx.z);
    int xcd = L & 7, j = L >> 3;
    int ff  = fx * fy;
    int zw  = xcd / ff;
    int rr  = xcd % ff;
    int nxf = gridDim.x / fx;
    int bnw = (j % nxf) * fx + (rr % fx);
    int bmw = (j / nxf) * fy + (rr / fx);
    int bn  = bnw * 128, bm = bmw * 128;

    int wm   = (wv & 1) * 64, wn = (wv >> 1) * 64;
    int l16  = lane & 15, g16 = lane >> 4;

    int kc   = Kd / gridDim.z;
    int zoff = zw * kc;

    const __bf16* ag0 = A  + (size_t)(bm + (tid >> 2)) * Kd + zoff + (tid & 3) * 8;
    const __bf16* ag1 = ag0 + (size_t)64 * Kd;
    const __bf16* bg0 = Bt + (size_t)(bn + (tid >> 2)) * Kd + zoff + (tid & 3) * 8;
    const __bf16* bg1 = bg0 + (size_t)64 * Kd;
    __bf16* al0 = &As[tid * 8];
    __bf16* al1 = &As[2048 + tid * 8];
    __bf16* bl0 = &Bs[tid * 8];
    __bf16* bl1 = &Bs[2048 + tid * 8];

    floatx4 acc[4][4] = {};

    for (int k0 = 0; k0 < kc; k0 += 32) {
        __syncthreads();
        load_lds16(ag0, al0); load_lds16(ag1, al1);
        load_lds16(bg0, bl0); load_lds16(bg1, bl1);
        ag0 += 32; ag1 += 32; bg0 += 32; bg1 += 32;
        __syncthreads();
        bf16x8 af[4], bfr[4];
#pragma unroll
        for (int i = 0; i < 4; ++i)
            af[i] = *(const bf16x8*)&As[(wm + i * 16 + l16) * 32 + g16 * 8];
#pragma unroll
        for (int jj = 0; jj < 4; ++jj)
            bfr[jj] = *(const bf16x8*)&Bs[(wn + jj * 16 + l16) * 32 + g16 * 8];
#pragma unroll
        for (int i = 0; i < 4; ++i)
#pragma unroll
            for (int jj = 0; jj < 4; ++jj)
                acc[i][jj] = __builtin_amdgcn_mfma_f32_16x16x32_bf16(af[i], bfr[jj], acc[i][jj], 0, 0, 0);
    }

    __bf16* Cp = (zw == 0) ? cb : cbalt + (size_t)(zw - 1) * M * N;
    const float* bz = (zw == 0) ? bias : nullptr;

#pragma unroll
    for (int jj = 0; jj < 4; ++jj) {
        int col  = bn + wn + jj * 16 + l16;
        float sc = (col < split) ? scale0 : scale1;
        float bv = bz ? bz[col] : 0.f;
#pragma unroll
        for (int i = 0; i < 4; ++i) {
            int row0 = bm + wm + i * 16 + g16 * 4;
#pragma unroll
            for (int r = 0; r < 4; ++r) {
                float v = acc[i][jj][r] * sc + bv;
                if (RELU) v = fmaxf(v, 0.f);
                Cp[(size_t)(row0 + r) * N + col] = (__bf16)v;
            }
        }
    }
}

// ------------------------------------------------------- flash attention
// S^T = K·Q^T per tile: each lane owns ONE q-row (q = lane&15). O kept
// transposed (A=V^T, B=P). Optional q2: second split-K partial of Q, summed
// during staging (fuses ca_q's split-K reduction for free).
__launch_bounds__(256, 4)
__global__ void attn_kernel(const __bf16* __restrict__ qb, const __bf16* __restrict__ q2,
                            const __bf16* __restrict__ kb, const __bf16* __restrict__ vt,
                            int ldq, int ldk,
                            __bf16* __restrict__ out, int causal, int Tc) {
    constexpr int T = 1024;
    __shared__ alignas(16) __bf16 Qs[64 * 72];
    __shared__ alignas(16) __bf16 Ks[64 * 72];
    __shared__ alignas(16) __bf16 Vs[64 * 72];
    __shared__ alignas(16) __bf16 Ps[4][16 * 72];

    int tid = threadIdx.x;
    int wv = tid >> 6, lane = tid & 63;
    int qt = (blockIdx.x + 4 * blockIdx.z) & 15;   // balance causal work per CU
    int h = blockIdx.y, b = blockIdx.z;
    int l16 = lane & 15, g16 = lane >> 4;

#pragma unroll
    for (int cc = 0; cc < 2; ++cc) {
        int c = tid + cc * 256;
        int r = c >> 3, s8 = (c & 7) * 8;
        size_t go = (size_t)(b * T + qt * 64 + r) * ldq + h * 64 + s8;
        bf16x8 qv = *(const bf16x8*)(qb + go);
        if (q2) {
            bf16x8 q2v = *(const bf16x8*)(q2 + go);
#pragma unroll
            for (int e = 0; e < 8; ++e) qv[e] = (__bf16)((float)qv[e] + (float)q2v[e]);
        }
        *(bf16x8*)&Qs[r * 72 + s8] = qv;
    }

    floatx4 oacc[4] = {};
    float mi = -1e30f, li = 0.f;

    int ktmax = causal ? (qt + 1) : (Tc / 64);
    for (int kt = 0; kt < ktmax; ++kt) {
        __syncthreads();
#pragma unroll
        for (int cc = 0; cc < 2; ++cc) {
            int c = tid + cc * 256;
            int r = c >> 3, s8 = (c & 7) * 8;
            bf16x8 kv8 = *(const bf16x8*)(kb + (size_t)(b * Tc + kt * 64 + r) * ldk + h * 64 + s8);
            *(bf16x8*)&Ks[r * 72 + s8] = kv8;
            bf16x8 vv8 = *(const bf16x8*)(vt + ((size_t)(b * 16 + h) * 64 + r) * Tc + kt * 64 + s8);
            *(bf16x8*)&Vs[r * 72 + s8] = vv8;
        }
        __syncthreads();

        floatx4 sacc[4] = {};
#pragma unroll
        for (int kk = 0; kk < 2; ++kk) {
            bf16x8 bq = *(const bf16x8*)&Qs[(wv * 16 + l16) * 72 + kk * 32 + g16 * 8];
#pragma unroll
            for (int j = 0; j < 4; ++j) {
                bf16x8 ak = *(const bf16x8*)&Ks[(j * 16 + l16) * 72 + kk * 32 + g16 * 8];
                sacc[j] = __builtin_amdgcn_mfma_f32_16x16x32_bf16(ak, bq, sacc[j], 0, 0, 0);
            }
        }
        if (causal && kt == qt) {
            int qloc = wv * 16 + l16;
#pragma unroll
            for (int j = 0; j < 4; ++j)
#pragma unroll
                for (int r = 0; r < 4; ++r)
                    if (j * 16 + g16 * 4 + r > qloc) sacc[j][r] = -1e30f;
        }

        float mt = -1e30f;
#pragma unroll
        for (int j = 0; j < 4; ++j)
#pragma unroll
            for (int r = 0; r < 4; ++r) mt = fmaxf(mt, sacc[j][r]);
        mt = fmaxf(mt, __shfl_xor(mt, 16));
        mt = fmaxf(mt, __shfl_xor(mt, 32));
        float mnew  = fmaxf(mi, mt);
        float alpha = __expf(mi - mnew);
        mi = mnew;
        float ls = 0.f;
#pragma unroll
        for (int j = 0; j < 4; ++j) {
            bf16x4 pk;
#pragma unroll
            for (int r = 0; r < 4; ++r) {
                float p = __expf(sacc[j][r] - mnew);
                ls += p;
                pk[r] = (__bf16)p;
            }
            *(bf16x4*)&Ps[wv][l16 * 72 + j * 16 + g16 * 4] = pk;
        }
        ls += __shfl_xor(ls, 16);
        ls += __shfl_xor(ls, 32);
        li = li * alpha + ls;
#pragma unroll
        for (int j = 0; j < 4; ++j) {
            oacc[j][0] *= alpha; oacc[j][1] *= alpha;
            oacc[j][2] *= alpha; oacc[j][3] *= alpha;
        }
#pragma unroll
        for (int kk = 0; kk < 2; ++kk) {
            bf16x8 bp = *(const bf16x8*)&Ps[wv][l16 * 72 + kk * 32 + g16 * 8];
#pragma unroll
            for (int j = 0; j < 4; ++j) {
                bf16x8 av = *(const bf16x8*)&Vs[(j * 16 + l16) * 72 + kk * 32 + g16 * 8];
                oacc[j] = __builtin_amdgcn_mfma_f32_16x16x32_bf16(av, bp, oacc[j], 0, 0, 0);
            }
        }
    }

    __syncthreads();
    float inv = 1.f / li;
#pragma unroll
    for (int j = 0; j < 4; ++j) {
        bf16x4 ok;
#pragma unroll
        for (int r = 0; r < 4; ++r) ok[r] = (__bf16)(oacc[j][r] * inv);
        *(bf16x4*)&Ks[(wv * 16 + l16) * 72 + j * 16 + g16 * 4] = ok;
    }
    int rr = lane >> 2, c4 = (lane & 3) * 16;
    bf16x8 o0 = *(const bf16x8*)&Ks[(wv * 16 + rr) * 72 + c4];
    bf16x8 o1 = *(const bf16x8*)&Ks[(wv * 16 + rr) * 72 + c4 + 8];
    size_t ob = (size_t)(b * T + qt * 64 + wv * 16 + rr) * EMB + h * 64 + c4;
    *(bf16x8*)&out[ob]     = o0;
    *(bf16x8*)&out[ob + 8] = o1;
}

// --------------------------- residual + bf16 split-K partials + layernorm
// y = LN(res + sum_{i<np} pb[i*PSTRIDE + .]) * g + b
__launch_bounds__(256)
__global__ void ln_kernel(const float* __restrict__ res,
                          const __bf16* __restrict__ pb, int np,
                          const float* __restrict__ g, const float* __restrict__ be,
                          float* __restrict__ outf, __bf16* __restrict__ outb) {
    __shared__ float red[8];
    int row = blockIdx.x, tid = threadIdx.x;
    size_t base = (size_t)row * EMB;
    float4 v = ((const float4*)(res + base))[tid];
    for (int i = 0; i < np; ++i) {
        bf16x4 u = *(const bf16x4*)(pb + i * PSTRIDE + base + tid * 4);
        v.x += (float)u[0]; v.y += (float)u[1];
        v.z += (float)u[2]; v.w += (float)u[3];
    }
    float s  = v.x + v.y + v.z + v.w;
    float ss = v.x * v.x + v.y * v.y + v.z * v.z + v.w * v.w;
#pragma unroll
    for (int o = 1; o < 64; o <<= 1) { s += __shfl_xor(s, o); ss += __shfl_xor(ss, o); }
    if ((tid & 63) == 0) { red[(tid >> 6) * 2] = s; red[(tid >> 6) * 2 + 1] = ss; }
    __syncthreads();
    s  = red[0] + red[2] + red[4] + red[6];
    ss = red[1] + red[3] + red[5] + red[7];
    float mu  = s * (1.0f / 1024.0f);
    float var = ss * (1.0f / 1024.0f) - mu * mu;
    float rs  = rsqrtf(var + 1e-5f);
    float4 gg = ((const float4*)g)[tid];
    float4 bb = ((const float4*)be)[tid];
    float4 y;
    y.x = (v.x - mu) * rs * gg.x + bb.x;
    y.y = (v.y - mu) * rs * gg.y + bb.y;
    y.z = (v.z - mu) * rs * gg.z + bb.z;
    y.w = (v.w - mu) * rs * gg.w + bb.w;
    ((float4*)(outf + base))[tid] = y;
    if (outb) {
        bf16x4 o;
        o[0] = (__bf16)y.x; o[1] = (__bf16)y.y; o[2] = (__bf16)y.z; o[3] = (__bf16)y.w;
        *(bf16x4*)(outb + base + tid * 4) = o;
    }
}

// ---------------------------------------------------------------- launch
extern "C" void kernel_launch(void* const* d_in, const int* in_sizes, int n_in,
                              void* d_out, int out_size, void* d_ws, size_t ws_size,
                              hipStream_t stream) {
    const float* x     = (const float*)d_in[0];
    const float* ctx   = (const float*)d_in[1];
    const float* sa_wq = (const float*)d_in[2];
    const float* sa_wk = (const float*)d_in[3];
    const float* sa_wv = (const float*)d_in[4];
    const float* sa_wo = (const float*)d_in[5];
    const float* sa_bo = (const float*)d_in[6];
    const float* ca_wq = (const float*)d_in[7];
    const float* ca_wk = (const float*)d_in[8];
    const float* ca_wv = (const float*)d_in[9];
    const float* ca_wo = (const float*)d_in[10];
    const float* ca_bo = (const float*)d_in[11];
    const float* n1_g = (const float*)d_in[12];
    const float* n1_b = (const float*)d_in[13];
    const float* n2_g = (const float*)d_in[14];
    const float* n2_b = (const float*)d_in[15];
    const float* n3_g = (const float*)d_in[16];
    const float* n3_b = (const float*)d_in[17];
    const float* ff_w1 = (const float*)d_in[18];
    const float* ff_b1 = (const float*)d_in[19];
    const float* ff_w2 = (const float*)d_in[20];
    const float* ff_b2 = (const float*)d_in[21];

    size_t off = 0;
    auto alloc = [&](size_t bytes) {
        void* p = (char*)d_ws + off;
        off += (bytes + 255) & ~(size_t)255;
        return p;
    };
    __bf16* w_sa_qkvT = (__bf16*)alloc((size_t)3 * EMB * EMB * 2);
    __bf16* w_sa_oT   = (__bf16*)alloc((size_t)EMB * EMB * 2);
    __bf16* w_ca_qT   = (__bf16*)alloc((size_t)EMB * EMB * 2);
    __bf16* w_ca_kvT  = (__bf16*)alloc((size_t)2 * EMB * EMB * 2);
    __bf16* w_ca_oT   = (__bf16*)alloc((size_t)EMB * EMB * 2);
    __bf16* w1T       = (__bf16*)alloc((size_t)HIDN * EMB * 2);
    __bf16* w2T       = (__bf16*)alloc((size_t)EMB * HIDN * 2);
    __bf16* xb        = (__bf16*)alloc((size_t)MROWS * EMB * 2);     // 8 MB
    __bf16* qkv       = (__bf16*)alloc((size_t)MROWS * 3 * EMB * 2); // 24 MB, adjacent to xb
    __bf16* ao        = (__bf16*)alloc((size_t)MROWS * EMB * 2);     // 8 MB
    __bf16* hid       = (__bf16*)alloc((size_t)MROWS * HIDN * 2);    // 32 MB
    __bf16* x1b       = (__bf16*)alloc((size_t)MROWS * EMB * 2);     // 8 MB
    __bf16* vt        = (__bf16*)alloc((size_t)MROWS * EMB * 2);     // 8 MB
    float* res1       = (float*)alloc((size_t)MROWS * EMB * 4);
    float* res2       = (float*)alloc((size_t)MROWS * EMB * 4);

    __bf16* qx0 = qkv;                         // ca q partial 0
    __bf16* qx1 = hid;                         // ca q partial 1 (hid dead until ff1)
    __bf16* kvc = qkv + PSTRIDE;               // ca k,v
    // bf16 split-K partial overlays (liveness-checked):
    // attn-proj partials (2x8MB) -> qkv region (dead after attn consumed it)
    __bf16* pbo = qkv;
    // ff2 partials (4x8MB) -> xb+qkv contiguous region (all dead at ff2)
    __bf16* pbf = xb;

    const float s4 = 0.17677669529663687f;  // 1024^-0.25
    dim3 tb(32, 8);

    TC8 tc;
    tc.s[0] = sa_wq; tc.d[0] = w_sa_qkvT;
    tc.s[1] = sa_wk; tc.d[1] = w_sa_qkvT + (size_t)EMB * EMB;
    tc.s[2] = sa_wv; tc.d[2] = w_sa_qkvT + (size_t)2 * EMB * EMB;
    tc.s[3] = sa_wo; tc.d[3] = w_sa_oT;
    tc.s[4] = ca_wq; tc.d[4] = w_ca_qT;
    tc.s[5] = ca_wk; tc.d[5] = w_ca_kvT;
    tc.s[6] = ca_wv; tc.d[6] = w_ca_kvT + (size_t)EMB * EMB;
    tc.s[7] = ca_wo; tc.d[7] = w_ca_oT;
    transpose_cast8_kernel<<<dim3(32, 32, 8), tb, 0, stream>>>(tc);
    transpose_cast_kernel<<<dim3(128, 32), tb, 0, stream>>>(ff_w1, w1T, EMB, HIDN);
    transpose_cast_kernel<<<dim3(32, 128), tb, 0, stream>>>(ff_w2, w2T, HIDN, EMB);

    // ---- self attention ----
    cast_bf16_kernel<<<4096, 256, 0, stream>>>(x, xb, MROWS * EMB);
    gemm_bt<0><<<dim3(24, 32), 256, 0, stream>>>(xb, w_sa_qkvT, qkv, nullptr, nullptr,
        MROWS, 3 * EMB, EMB, s4, 1.f, 2048, 2, 4);
    transpose_v_kernel<<<dim3(32, 2, 64), tb, 0, stream>>>(qkv + 2 * EMB, vt, 3 * EMB, 1024);
    attn_kernel<<<dim3(16, 16, 4), 256, 0, stream>>>(qkv, nullptr, qkv + EMB, vt,
                                                     3 * EMB, 3 * EMB, ao, 1, 1024);
    gemm_bt<0><<<dim3(8, 32, 2), 256, 0, stream>>>(ao, w_sa_oT, pbo, pbo + PSTRIDE, sa_bo,
        MROWS, EMB, EMB, 1.f, 1.f, 0, 2, 2);
    ln_kernel<<<4096, 256, 0, stream>>>(x, pbo, 2, n1_g, n1_b, res1, x1b);

    // ---- cross attention ----
    cast_bf16_kernel<<<4096, 256, 0, stream>>>(ctx, xb, MROWS * EMB);  // cb
    gemm_bt<0><<<dim3(16, 32), 256, 0, stream>>>(xb, w_ca_kvT, kvc, nullptr, nullptr,
        MROWS, 2 * EMB, EMB, s4, 1.f, 1024, 2, 4);
    gemm_bt<0><<<dim3(8, 32, 2), 256, 0, stream>>>(x1b, w_ca_qT, qx0, qx1, nullptr,
        MROWS, EMB, EMB, s4, s4, 1 << 30, 2, 2);
    transpose_v_kernel<<<dim3(32, 2, 64), tb, 0, stream>>>(kvc + EMB, vt, 2 * EMB, 1024);
    attn_kernel<<<dim3(16, 16, 4), 256, 0, stream>>>(qx0, qx1, kvc, vt,
                                                     EMB, 2 * EMB, ao, 0, 1024);
    gemm_bt<0><<<dim3(8, 32, 2), 256, 0, stream>>>(ao, w_ca_oT, pbo, pbo + PSTRIDE, ca_bo,
        MROWS, EMB, EMB, 1.f, 1.f, 0, 2, 2);
    ln_kernel<<<4096, 256, 0, stream>>>(res1, pbo, 2, n2_g, n2_b, res2, x1b);

    // ---- FFN ----
    gemm_bt<1><<<dim3(32, 32), 256, 0, stream>>>(x1b, w1T, hid, nullptr, ff_b1,
        MROWS, HIDN, EMB, 1.f, 1.f, 0, 2, 4);
    gemm_bt<0><<<dim3(8, 32, 4), 256, 0, stream>>>(hid, w2T, pbf, pbf + PSTRIDE, ff_b2,
        MROWS, EMB, HIDN, 1.f, 1.f, 0, 1, 2);
    ln_kernel<<<4096, 256, 0, stream>>>(res2, pbf, 4, n3_g, n3_b, (float*)d_out, nullptr);
}